// Round 5
// baseline (118.693 us; speedup 1.0000x reference)
//
#include <hip/hip_runtime.h>
#include <hip/hip_bf16.h>
#include <stdint.h>

// BatchHardTripletLoss: N=4096, D=512, C=128, margin=0.3
// dist monotone-decreasing in gram => hardest-pos = min gram (same label, j!=i),
// hardest-neg = max gram (diff label). Gram symmetric => upper-triangular
// 128x128 tiles (528); off-diag tiles feed row- and col-direction reductions.
// R5: barrier-free gram K-loop. MFMA A/B fragments for 16x16x32 are
// 16B-contiguous in row-major Ebf (frag[m=l16][k=quad*8+j]) => load them
// DIRECTLY from global (L2-resident, 4 MB), no LDS staging, no __syncthreads
// in the K-loop. All 16 K-step offsets (it*64 B <= 960) fold into the load
// immediate. R2's LDS version was barrier-serialized at 2.06 blocks/CU;
// R4 (BT=64) doubled staging traffic (N^2/BT scaling) — both reverted.

#define NROW 4096
#define DIM  512
#define MARGIN 0.3f
#define BT 128
#define KITERS 16                          // K-chunks of 32
#define NTILE (NROW / BT)                  // 32
#define NPAIR (NTILE * (NTILE + 1) / 2)    // 528
#define POS_INIT 0xFFFFFFFFu
#define NEG_INIT 0u

typedef __attribute__((ext_vector_type(8))) __bf16 bf16x8;
typedef __attribute__((ext_vector_type(4))) float  f32x4;

// monotone float<->uint: order-preserving for atomicMin/Max on unsigned.
// enc(finite f) never equals POS_INIT (needs NaN) nor NEG_INIT (needs -NaN),
// so init sentinels double as "no positive/negative seen" flags.
__device__ __forceinline__ unsigned enc(float f) {
    unsigned u = __float_as_uint(f);
    return (u & 0x80000000u) ? ~u : (u | 0x80000000u);
}
__device__ __forceinline__ float dec(unsigned e) {
    return (e & 0x80000000u) ? __uint_as_float(e & 0x7fffffffu)
                             : __uint_as_float(~e);
}

__device__ __forceinline__ unsigned short f2bf(float f) {
    __hip_bfloat16 h = __float2bfloat16(f);
    return *reinterpret_cast<unsigned short*>(&h);
}

// ---- kernel 1: L2-normalize rows -> bf16, + init reduction arrays ----
// one wave per row; 4 waves/block; 1024 blocks (first 16 also init pos/neg)
__global__ void tl_norm(const float* __restrict__ E,
                        __hip_bfloat16* __restrict__ Ebf,
                        unsigned* __restrict__ posArr,
                        unsigned* __restrict__ negArr) {
    if (blockIdx.x < 16) {
        int t = blockIdx.x * 256 + threadIdx.x;   // covers 4096
        posArr[t] = POS_INIT;
        negArr[t] = NEG_INIT;
    }
    int wave = threadIdx.x >> 6;
    int lane = threadIdx.x & 63;
    int row  = blockIdx.x * 4 + wave;

    const float4* src = (const float4*)(E + (size_t)row * DIM); // 128 float4/row
    float4 v0 = src[lane];
    float4 v1 = src[lane + 64];
    float ss = v0.x*v0.x + v0.y*v0.y + v0.z*v0.z + v0.w*v0.w
             + v1.x*v1.x + v1.y*v1.y + v1.z*v1.z + v1.w*v1.w;
    #pragma unroll
    for (int m = 32; m >= 1; m >>= 1) ss += __shfl_xor(ss, m);
    float inv = 1.0f / fmaxf(sqrtf(ss), 1e-12f);

    ushort4 o0, o1;
    o0.x = f2bf(v0.x * inv); o0.y = f2bf(v0.y * inv);
    o0.z = f2bf(v0.z * inv); o0.w = f2bf(v0.w * inv);
    o1.x = f2bf(v1.x * inv); o1.y = f2bf(v1.y * inv);
    o1.z = f2bf(v1.z * inv); o1.w = f2bf(v1.w * inv);
    ushort4* dst = (ushort4*)(Ebf + (size_t)row * DIM);
    dst[lane]      = o0;
    dst[lane + 64] = o1;
}

// ---- kernel 2: upper-triangular 128x128 gram tiles, direct-global MFMA ----
// 4 waves in 2x2; each wave 64x64 via 4x4 of 16x16x32 MFMA. Fragments loaded
// straight from global (no LDS, no K-loop barriers).
__global__ void __launch_bounds__(256, 2)
tl_gram(const __hip_bfloat16* __restrict__ Ebf,
        const int* __restrict__ labels,
        unsigned* __restrict__ posArr,
        unsigned* __restrict__ negArr) {
    __shared__ int rowLab[BT];
    __shared__ int colLab[BT];

    // triangular decode: blockIdx.x -> (bi, bj) with bi <= bj
    int t = blockIdx.x, bi = 0, rowlen = NTILE;
    while (t >= rowlen) { t -= rowlen; rowlen--; bi++; }
    const int bj = bi + t;

    const int tid  = threadIdx.x;
    const int wave = tid >> 6;
    const int lane = tid & 63;
    const int quad = lane >> 4;
    const int l16  = lane & 15;
    const int wr   = wave >> 1;   // wave row (0..1): rows wr*64..+63
    const int wc   = wave & 1;    // wave col (0..1): cols wc*64..+63
    const int tileI = bi * BT;
    const int tileJ = bj * BT;
    const bool diag = (bi == bj);

    if (tid < BT) rowLab[tid] = labels[tileI + tid];
    else          colLab[tid - BT] = labels[tileJ + (tid - BT)];
    __syncthreads();   // the only barrier: labels visible for epilogue

    // fragment base pointers: frag[m=l16][k=quad*8+j] is 16B-contiguous
    const __hip_bfloat16* aP[4];
    const __hip_bfloat16* bP[4];
    #pragma unroll
    for (int mi = 0; mi < 4; mi++)
        aP[mi] = Ebf + (size_t)(tileI + wr * 64 + mi * 16 + l16) * DIM + quad * 8;
    #pragma unroll
    for (int ni = 0; ni < 4; ni++)
        bP[ni] = Ebf + (size_t)(tileJ + wc * 64 + ni * 16 + l16) * DIM + quad * 8;

    f32x4 acc[4][4] = {};

    #pragma unroll
    for (int it = 0; it < KITERS; it++) {
        bf16x8 a[4], b[4];
        #pragma unroll
        for (int mi = 0; mi < 4; mi++)
            a[mi] = *(const bf16x8*)(aP[mi] + it * 32);   // offset imm: it*64 B
        #pragma unroll
        for (int ni = 0; ni < 4; ni++)
            b[ni] = *(const bf16x8*)(bP[ni] + it * 32);

        #pragma unroll
        for (int mi = 0; mi < 4; mi++)
            #pragma unroll
            for (int ni = 0; ni < 4; ni++)
                acc[mi][ni] = __builtin_amdgcn_mfma_f32_16x16x32_bf16(
                    a[mi], b[ni], acc[mi][ni], 0, 0, 0);
    }

    // C/D layout: col = wc*64+ni*16+l16 (lane), row = wr*64+mi*16+quad*4+reg
    int rl[16], cl[4], clocv[4];
    #pragma unroll
    for (int mi = 0; mi < 4; mi++)
        #pragma unroll
        for (int reg = 0; reg < 4; reg++)
            rl[mi * 4 + reg] = rowLab[wr * 64 + mi * 16 + quad * 4 + reg];
    #pragma unroll
    for (int ni = 0; ni < 4; ni++) {
        clocv[ni] = wc * 64 + ni * 16 + l16;
        cl[ni] = colLab[clocv[ni]];
    }

    // ---- row pass: reduce over this tile's columns, for rows of tileI ----
    #pragma unroll
    for (int mi = 0; mi < 4; mi++) {
        #pragma unroll
        for (int reg = 0; reg < 4; reg++) {
            const int rloc = wr * 64 + mi * 16 + quad * 4 + reg;
            const int lr   = rl[mi * 4 + reg];
            const int gi   = tileI + rloc;
            float pmin =  INFINITY;
            float nmax = -INFINITY;
            #pragma unroll
            for (int ni = 0; ni < 4; ni++) {
                const int gj  = tileJ + clocv[ni];
                const float g = acc[mi][ni][reg];
                const bool same = (lr == cl[ni]);
                if (same && gi != gj) pmin = fminf(pmin, g);
                if (!same)            nmax = fmaxf(nmax, g);
            }
            #pragma unroll
            for (int m = 1; m < 16; m <<= 1) {
                pmin = fminf(pmin, __shfl_xor(pmin, m));
                nmax = fmaxf(nmax, __shfl_xor(nmax, m));
            }
            if (l16 == 0) {
                if (pmin <  INFINITY) atomicMin(&posArr[gi], enc(pmin));
                if (nmax > -INFINITY) atomicMax(&negArr[gi], enc(nmax));
            }
        }
    }

    // ---- col pass (off-diag only): reduce over rows, for rows of tileJ ----
    if (!diag) {
        #pragma unroll
        for (int ni = 0; ni < 4; ni++) {
            const int lc = cl[ni];
            const int gj = tileJ + clocv[ni];
            float pmin =  INFINITY;
            float nmax = -INFINITY;
            #pragma unroll
            for (int mi = 0; mi < 4; mi++) {
                #pragma unroll
                for (int reg = 0; reg < 4; reg++) {
                    const float g = acc[mi][ni][reg];
                    const bool same = (rl[mi * 4 + reg] == lc);
                    if (same) pmin = fminf(pmin, g);
                    else      nmax = fmaxf(nmax, g);
                }
            }
            pmin = fminf(pmin, __shfl_xor(pmin, 16));
            pmin = fminf(pmin, __shfl_xor(pmin, 32));
            nmax = fmaxf(nmax, __shfl_xor(nmax, 16));
            nmax = fmaxf(nmax, __shfl_xor(nmax, 32));
            if (quad == 0) {
                if (pmin <  INFINITY) atomicMin(&posArr[gj], enc(pmin));
                if (nmax > -INFINITY) atomicMax(&negArr[gj], enc(nmax));
            }
        }
    }
}

// ---- kernel 3: per-row loss + mean over valid rows ----
__global__ void tl_final(const unsigned* __restrict__ posArr,
                         const unsigned* __restrict__ negArr,
                         float* __restrict__ out) {
    const int tid = threadIdx.x; // 256 threads
    float sum = 0.0f;
    int   count = 0;
    for (int i = tid; i < NROW; i += 256) {
        const unsigned pe = posArr[i];
        const unsigned ne = negArr[i];
        const bool valid = (pe != POS_INIT) && (ne != NEG_INIT);
        const float dap = sqrtf(fmaxf(2.0f - 2.0f * dec(pe), 0.0f));
        const float dan = sqrtf(fmaxf(2.0f - 2.0f * dec(ne), 0.0f));
        const float per = fmaxf(dap - dan + MARGIN, 0.0f);
        if (valid) { sum += per; count += 1; }
    }
    #pragma unroll
    for (int m = 32; m >= 1; m >>= 1) {
        sum   += __shfl_xor(sum, m);
        count += __shfl_xor(count, m);
    }
    __shared__ float ssum[4];
    __shared__ int   scnt[4];
    const int wave = tid >> 6, lane = tid & 63;
    if (lane == 0) { ssum[wave] = sum; scnt[wave] = count; }
    __syncthreads();
    if (tid == 0) {
        float s = ssum[0] + ssum[1] + ssum[2] + ssum[3];
        int   c = scnt[0] + scnt[1] + scnt[2] + scnt[3];
        out[0] = (c > 0) ? (s / (float)c) : 0.0f;
    }
}

extern "C" void kernel_launch(void* const* d_in, const int* in_sizes, int n_in,
                              void* d_out, int out_size, void* d_ws, size_t ws_size,
                              hipStream_t stream) {
    const float* E      = (const float*)d_in[0];
    const int*   labels = (const int*)d_in[1];
    float*       out    = (float*)d_out;

    char* ws = (char*)d_ws;
    __hip_bfloat16* Ebf   = (__hip_bfloat16*)ws;                       // 4 MB
    unsigned* posArr      = (unsigned*)(ws + (size_t)NROW * DIM * 2);  // 16 KB
    unsigned* negArr      = posArr + NROW;                             // 16 KB

    tl_norm<<<NROW / 4, 256, 0, stream>>>(E, Ebf, posArr, negArr);
    tl_gram<<<NPAIR, 256, 0, stream>>>(Ebf, labels, posArr, negArr);
    tl_final<<<1, 256, 0, stream>>>(posArr, negArr, out);
}

// Round 6
// 93.570 us; speedup vs baseline: 1.2685x; 1.2685x over previous
//
#include <hip/hip_runtime.h>
#include <hip/hip_bf16.h>
#include <stdint.h>

// BatchHardTripletLoss: N=4096, D=512, C=128, margin=0.3
// hardest-pos = min gram (same label, j!=i), hardest-neg = max gram (diff
// label); dist=sqrt(2-2g) monotone. Triangular 128x128 tiles (528 blocks).
// R6: fragment-major packed layout. tl_norm writes Epack so that one wave's
// 16-row x 32-k MFMA fragment group is ONE fully-coalesced 16B/lane load:
//   elem(row,k) -> block(row/16, k/32) [1KB], lane=((k>>3)&3)*16 + row%16,
//   byte = blk*1024 + lane*16 + (k&7)*2
// Gram K-loop: 8 coalesced global loads + 16 MFMA per iter, NO LDS, NO
// barriers — compiler schedules loads ahead with fine vmcnt (AITER pattern).
// R5 failed only on coalescing (row-major frag loads = 16-way scattered).

#define NROW 4096
#define DIM  512
#define MARGIN 0.3f
#define BT 128
#define KITERS 16                          // K-chunks of 32
#define NTILE (NROW / BT)                  // 32
#define NPAIR (NTILE * (NTILE + 1) / 2)    // 528
#define POS_INIT 0xFFFFFFFFu
#define NEG_INIT 0u

typedef __attribute__((ext_vector_type(8))) __bf16 bf16x8;
typedef __attribute__((ext_vector_type(4))) float  f32x4;

__device__ __forceinline__ unsigned enc(float f) {
    unsigned u = __float_as_uint(f);
    return (u & 0x80000000u) ? ~u : (u | 0x80000000u);
}
__device__ __forceinline__ float dec(unsigned e) {
    return (e & 0x80000000u) ? __uint_as_float(e & 0x7fffffffu)
                             : __uint_as_float(~e);
}
__device__ __forceinline__ unsigned short f2bf(float f) {
    __hip_bfloat16 h = __float2bfloat16(f);
    return *reinterpret_cast<unsigned short*>(&h);
}

// ---- kernel 1: L2-normalize rows -> packed bf16 (fragment-major) ----
// one wave per row; coalesced fp32 reads; packed 8B stores.
__global__ void tl_norm(const float* __restrict__ E,
                        char* __restrict__ Epack,
                        unsigned* __restrict__ posArr,
                        unsigned* __restrict__ negArr) {
    if (blockIdx.x < 16) {
        int t = blockIdx.x * 256 + threadIdx.x;   // covers 4096
        posArr[t] = POS_INIT;
        negArr[t] = NEG_INIT;
    }
    const int wave = threadIdx.x >> 6;
    const int lane = threadIdx.x & 63;
    const int row  = blockIdx.x * 4 + wave;

    const float4* src = (const float4*)(E + (size_t)row * DIM); // 128 float4/row
    float4 v0 = src[lane];          // k = 4*lane .. +3
    float4 v1 = src[lane + 64];     // k = 256 + 4*lane .. +3
    float ss = v0.x*v0.x + v0.y*v0.y + v0.z*v0.z + v0.w*v0.w
             + v1.x*v1.x + v1.y*v1.y + v1.z*v1.z + v1.w*v1.w;
    #pragma unroll
    for (int m = 32; m >= 1; m >>= 1) ss += __shfl_xor(ss, m);
    float inv = 1.0f / fmaxf(sqrtf(ss), 1e-12f);

    ushort4 o0, o1;
    o0.x = f2bf(v0.x * inv); o0.y = f2bf(v0.y * inv);
    o0.z = f2bf(v0.z * inv); o0.w = f2bf(v0.w * inv);
    o1.x = f2bf(v1.x * inv); o1.y = f2bf(v1.y * inv);
    o1.z = f2bf(v1.z * inv); o1.w = f2bf(v1.w * inv);

    // packed address for k0 = 4*lane (+0/+256):
    //   kb = k0>>5, q = (k0>>3)&3, s = k0&7  (s = 0 or 4)
    const int g  = row >> 4;
    const int r  = row & 15;
    const int kbA = lane >> 3;              // v0: kb = (4l)>>5
    const int q   = (lane >> 1) & 3;
    const int sub = (lane & 1) * 8;         // byte offset within 16B chunk
    const size_t laneOff = (size_t)(q * 16 + r) * 16 + sub;
    char* base = Epack + (size_t)(g * 16) * 1024;
    *(ushort4*)(base + (size_t)(kbA    ) * 1024 + laneOff) = o0;
    *(ushort4*)(base + (size_t)(kbA + 8) * 1024 + laneOff) = o1;
}

// ---- kernel 2: upper-triangular 128x128 gram tiles, packed-global MFMA ----
// 4 waves in 2x2; each wave 64x64 via 4x4 of 16x16x32 MFMA. Fragments are
// single coalesced 16B/lane loads from Epack. No LDS/barriers in K-loop.
__global__ void __launch_bounds__(256, 2)
tl_gram(const char* __restrict__ Epack,
        const int* __restrict__ labels,
        unsigned* __restrict__ posArr,
        unsigned* __restrict__ negArr) {
    __shared__ int rowLab[BT];
    __shared__ int colLab[BT];

    // triangular decode: blockIdx.x -> (bi, bj) with bi <= bj
    int t = blockIdx.x, bi = 0, rowlen = NTILE;
    while (t >= rowlen) { t -= rowlen; rowlen--; bi++; }
    const int bj = bi + t;

    const int tid  = threadIdx.x;
    const int wave = tid >> 6;
    const int lane = tid & 63;
    const int quad = lane >> 4;
    const int l16  = lane & 15;
    const int wr   = wave >> 1;   // wave row (0..1): rows wr*64..+63
    const int wc   = wave & 1;    // wave col (0..1): cols wc*64..+63
    const int tileI = bi * BT;
    const int tileJ = bj * BT;
    const bool diag = (bi == bj);

    if (tid < BT) rowLab[tid] = labels[tileI + tid];
    else          colLab[tid - BT] = labels[tileJ + (tid - BT)];
    __syncthreads();   // labels visible for epilogue (only barrier)

    // per-mi/ni group base: 16-row group gA = tileI/16 + wr*4 + mi, stride
    // along K = 1KB per k-chunk. Lane offset lane*16 makes the load coalesced.
    const char* aP[4];
    const char* bP[4];
    #pragma unroll
    for (int mi = 0; mi < 4; mi++)
        aP[mi] = Epack + (size_t)(tileI / 16 + wr * 4 + mi) * 16384 + (size_t)lane * 16;
    #pragma unroll
    for (int ni = 0; ni < 4; ni++)
        bP[ni] = Epack + (size_t)(tileJ / 16 + wc * 4 + ni) * 16384 + (size_t)lane * 16;

    f32x4 acc[4][4] = {};

    #pragma unroll
    for (int kc = 0; kc < KITERS; kc++) {
        bf16x8 a[4], b[4];
        #pragma unroll
        for (int mi = 0; mi < 4; mi++)
            a[mi] = *(const bf16x8*)(aP[mi] + kc * 1024);
        #pragma unroll
        for (int ni = 0; ni < 4; ni++)
            b[ni] = *(const bf16x8*)(bP[ni] + kc * 1024);

        #pragma unroll
        for (int mi = 0; mi < 4; mi++)
            #pragma unroll
            for (int ni = 0; ni < 4; ni++)
                acc[mi][ni] = __builtin_amdgcn_mfma_f32_16x16x32_bf16(
                    a[mi], b[ni], acc[mi][ni], 0, 0, 0);
    }

    // C/D layout: col = wc*64+ni*16+l16 (lane), row = wr*64+mi*16+quad*4+reg
    int rl[16], cl[4], clocv[4];
    #pragma unroll
    for (int mi = 0; mi < 4; mi++)
        #pragma unroll
        for (int reg = 0; reg < 4; reg++)
            rl[mi * 4 + reg] = rowLab[wr * 64 + mi * 16 + quad * 4 + reg];
    #pragma unroll
    for (int ni = 0; ni < 4; ni++) {
        clocv[ni] = wc * 64 + ni * 16 + l16;
        cl[ni] = colLab[clocv[ni]];
    }

    // ---- row pass: reduce over this tile's columns, for rows of tileI ----
    #pragma unroll
    for (int mi = 0; mi < 4; mi++) {
        #pragma unroll
        for (int reg = 0; reg < 4; reg++) {
            const int rloc = wr * 64 + mi * 16 + quad * 4 + reg;
            const int lr   = rl[mi * 4 + reg];
            const int gi   = tileI + rloc;
            float pmin =  INFINITY;
            float nmax = -INFINITY;
            #pragma unroll
            for (int ni = 0; ni < 4; ni++) {
                const int gj  = tileJ + clocv[ni];
                const float g = acc[mi][ni][reg];
                const bool same = (lr == cl[ni]);
                if (same && gi != gj) pmin = fminf(pmin, g);
                if (!same)            nmax = fmaxf(nmax, g);
            }
            #pragma unroll
            for (int m = 1; m < 16; m <<= 1) {
                pmin = fminf(pmin, __shfl_xor(pmin, m));
                nmax = fmaxf(nmax, __shfl_xor(nmax, m));
            }
            if (l16 == 0) {
                if (pmin <  INFINITY) atomicMin(&posArr[gi], enc(pmin));
                if (nmax > -INFINITY) atomicMax(&negArr[gi], enc(nmax));
            }
        }
    }

    // ---- col pass (off-diag only): reduce over rows, for rows of tileJ ----
    if (!diag) {
        #pragma unroll
        for (int ni = 0; ni < 4; ni++) {
            const int lc = cl[ni];
            const int gj = tileJ + clocv[ni];
            float pmin =  INFINITY;
            float nmax = -INFINITY;
            #pragma unroll
            for (int mi = 0; mi < 4; mi++) {
                #pragma unroll
                for (int reg = 0; reg < 4; reg++) {
                    const float g = acc[mi][ni][reg];
                    const bool same = (rl[mi * 4 + reg] == lc);
                    if (same) pmin = fminf(pmin, g);
                    else      nmax = fmaxf(nmax, g);
                }
            }
            pmin = fminf(pmin, __shfl_xor(pmin, 16));
            pmin = fminf(pmin, __shfl_xor(pmin, 32));
            nmax = fmaxf(nmax, __shfl_xor(nmax, 16));
            nmax = fmaxf(nmax, __shfl_xor(nmax, 32));
            if (quad == 0) {
                if (pmin <  INFINITY) atomicMin(&posArr[gj], enc(pmin));
                if (nmax > -INFINITY) atomicMax(&negArr[gj], enc(nmax));
            }
        }
    }
}

// ---- kernel 3: per-row loss + mean over valid rows ----
__global__ void tl_final(const unsigned* __restrict__ posArr,
                         const unsigned* __restrict__ negArr,
                         float* __restrict__ out) {
    const int tid = threadIdx.x; // 256 threads
    float sum = 0.0f;
    int   count = 0;
    for (int i = tid; i < NROW; i += 256) {
        const unsigned pe = posArr[i];
        const unsigned ne = negArr[i];
        const bool valid = (pe != POS_INIT) && (ne != NEG_INIT);
        const float dap = sqrtf(fmaxf(2.0f - 2.0f * dec(pe), 0.0f));
        const float dan = sqrtf(fmaxf(2.0f - 2.0f * dec(ne), 0.0f));
        const float per = fmaxf(dap - dan + MARGIN, 0.0f);
        if (valid) { sum += per; count += 1; }
    }
    #pragma unroll
    for (int m = 32; m >= 1; m >>= 1) {
        sum   += __shfl_xor(sum, m);
        count += __shfl_xor(count, m);
    }
    __shared__ float ssum[4];
    __shared__ int   scnt[4];
    const int wave = tid >> 6, lane = tid & 63;
    if (lane == 0) { ssum[wave] = sum; scnt[wave] = count; }
    __syncthreads();
    if (tid == 0) {
        float s = ssum[0] + ssum[1] + ssum[2] + ssum[3];
        int   c = scnt[0] + scnt[1] + scnt[2] + scnt[3];
        out[0] = (c > 0) ? (s / (float)c) : 0.0f;
    }
}

extern "C" void kernel_launch(void* const* d_in, const int* in_sizes, int n_in,
                              void* d_out, int out_size, void* d_ws, size_t ws_size,
                              hipStream_t stream) {
    const float* E      = (const float*)d_in[0];
    const int*   labels = (const int*)d_in[1];
    float*       out    = (float*)d_out;

    char* ws = (char*)d_ws;
    char* Epack           = ws;                                        // 4 MB packed
    unsigned* posArr      = (unsigned*)(ws + (size_t)NROW * DIM * 2);  // 16 KB
    unsigned* negArr      = posArr + NROW;                             // 16 KB

    tl_norm<<<NROW / 4, 256, 0, stream>>>(E, Epack, posArr, negArr);
    tl_gram<<<NPAIR, 256, 0, stream>>>(Epack, labels, posArr, negArr);
    tl_final<<<1, 256, 0, stream>>>(posArr, negArr, out);
}